// Round 20
// baseline (137.365 us; speedup 1.0000x reference)
//
#include <hip/hip_runtime.h>

// MultiHeadAttention (SAGAN reshape), B=C=1, T=3072, D=1024, H=16, head-dim 64.
// Round 20: the clean TLP test. R19's KVBLK=128 attn body + 4-way j-split
// across blocks (grid 1024) + launch_bounds(256,2) (keeps the proven VGPR-112
// codegen; R15's (256,4) spilled, R16's no-hint bloated to 136).
// 4 blocks/CU = 16 waves/CU (was 8 in every prior clean run).
// Epilogue = R15's verified 4-way log-sum merge.

typedef _Float16 v8h __attribute__((ext_vector_type(8)));
typedef _Float16 v4h __attribute__((ext_vector_type(4)));
typedef __fp16   v2pk __attribute__((ext_vector_type(2)));
typedef __fp16   v4pk __attribute__((ext_vector_type(4)));
typedef float    v4f __attribute__((ext_vector_type(4)));

#define TSEQ 3072
#define DM   1024
#define NH   16
#define XD   64
#define LOG2E 1.44269504f

__device__ __forceinline__ void async_load16(const void* g, void* l) {
  __builtin_amdgcn_global_load_lds(
      (const __attribute__((address_space(1))) unsigned int*)g,
      (__attribute__((address_space(3))) unsigned int*)l,
      16, 0, 0);
}

__device__ __forceinline__ float fexp2(float x) {
  float r; asm("v_exp_f32 %0, %1" : "=v"(r) : "v"(x)); return r;
}
__device__ __forceinline__ float flog2(float x) {
  float r; asm("v_log_f32 %0, %1" : "=v"(r) : "v"(x)); return r;
}

// ---------------- kernel 0: fp32 -> fp16 conversion -------------------------
extern "C" __global__ __launch_bounds__(256) void cvt_kernel(
    const float* __restrict__ x, const float* __restrict__ wq,
    const float* __restrict__ wk, const float* __restrict__ wv,
    _Float16* __restrict__ xb, _Float16* __restrict__ wb)
{
  const int NX4 = (TSEQ * DM) / 4;
  const int NT  = NX4 * 2;
  for (int i = blockIdx.x * blockDim.x + threadIdx.x; i < NT;
       i += gridDim.x * blockDim.x) {
    float4 v;
    _Float16* dst;
    if (i < NX4) {
      v = ((const float4*)x)[i];
      dst = xb + (size_t)i * 4;
    } else {
      const int j = i - NX4;
      const int n = j >> 8;
      if (n < 1024)      v = ((const float4*)wq)[j];
      else if (n < 2048) v = ((const float4*)wk)[j - 262144];
      else               v = ((const float4*)wv)[j - 524288];
      dst = wb + (size_t)j * 4;
    }
    v4h h;
    h[0] = (_Float16)v.x; h[1] = (_Float16)v.y;
    h[2] = (_Float16)v.z; h[3] = (_Float16)v.w;
    *(v4h*)dst = h;
  }
}

// ---------------- kernel 1: fused QKV GEMM (BK=32, row-major epilogue) ------
extern "C" __global__ __launch_bounds__(256) void qkv_gemm_kernel(
    const _Float16* __restrict__ xb, const _Float16* __restrict__ wb,
    const float* __restrict__ bq, const float* __restrict__ bk,
    const float* __restrict__ bv,
    _Float16* __restrict__ qlin, _Float16* __restrict__ klin,
    _Float16* __restrict__ vlin)
{
  __shared__ _Float16 As[128 * 32];
  __shared__ _Float16 Bs[128 * 32];
  const int tid = threadIdx.x;
  const int w = tid >> 6, l = tid & 63;
  const int li = l & 15, lg = l >> 4;
  const int wm = w >> 1, wn = w & 1;
  const int bid = blockIdx.x;                 // 576 = 72*8, bijective XCD swz
  const int swz = (bid & 7) * 72 + (bid >> 3);
  const int m0 = (swz / 24) * 128, n0 = (swz % 24) * 128;
  v4f acc[4][4] = {};
  const int srow = l >> 2;
  const int scol = (l & 3) * 8;
  for (int k0 = 0; k0 < DM; k0 += 32) {
#pragma unroll
    for (int c = 0; c < 2; ++c) {
      const int rbase = c * 64 + w * 16;
      async_load16(xb + (size_t)(m0 + rbase + srow) * DM + k0 + scol, &As[rbase * 32]);
      async_load16(wb + (size_t)(n0 + rbase + srow) * DM + k0 + scol, &Bs[rbase * 32]);
    }
    __syncthreads();
    v8h af[4], bf[4];
#pragma unroll
    for (int mi = 0; mi < 4; ++mi)
      af[mi] = *(const v8h*)&As[(wm * 64 + mi * 16 + li) * 32 + lg * 8];
#pragma unroll
    for (int ni = 0; ni < 4; ++ni)
      bf[ni] = *(const v8h*)&Bs[(wn * 64 + ni * 16 + li) * 32 + lg * 8];
#pragma unroll
    for (int mi = 0; mi < 4; ++mi)
#pragma unroll
      for (int ni = 0; ni < 4; ++ni)
        acc[mi][ni] = __builtin_amdgcn_mfma_f32_16x16x32_f16(
            af[mi], bf[ni], acc[mi][ni], 0, 0, 0);
    __syncthreads();
  }
  const int which = n0 >> 10;
  const int ebase = n0 & 1023;
  const float* bias = which == 0 ? bq : (which == 1 ? bk : bv);
  _Float16* outp = which == 0 ? qlin : (which == 1 ? klin : vlin);
#pragma unroll
  for (int mi = 0; mi < 4; ++mi)
#pragma unroll
    for (int r = 0; r < 4; ++r) {
      const int t = m0 + wm * 64 + mi * 16 + lg * 4 + r;
#pragma unroll
      for (int ni = 0; ni < 4; ++ni) {
        const int e = ebase + wn * 64 + ni * 16 + li;
        outp[(size_t)t * DM + e] = (_Float16)(acc[mi][ni][r] + bias[e]);
      }
    }
}

// ---------------- kernel 2: per-head repack ---------------------------------
extern "C" __global__ __launch_bounds__(256) void repack_kernel(
    const _Float16* __restrict__ qlin, const _Float16* __restrict__ klin,
    const _Float16* __restrict__ vlin,
    _Float16* __restrict__ qh, _Float16* __restrict__ kh,
    _Float16* __restrict__ vt)
{
  const int NE = NH * TSEQ * XD;   // 3145728
  for (int g = blockIdx.x * blockDim.x + threadIdx.x; g < 3 * NE;
       g += gridDim.x * blockDim.x) {
    if (g < 2 * NE) {
      const int gg = (g < NE) ? g : g - NE;
      const int xx = gg & 63;
      const int rest = gg >> 6;          // h*3072 + i
      const int h = rest / TSEQ;
      const int i = rest - h * TSEQ;
      const int t = xx * 48 + (i >> 6);
      const int e = ((i & 63) << 4) + h;
      if (g < NE) qh[gg] = qlin[t * DM + e];
      else        kh[gg] = (_Float16)((float)klin[t * DM + e] * LOG2E);
    } else {
      const int o = g - 2 * NE;
      const int j = o % TSEQ;
      const int rest = o / TSEQ;          // h*64 + x
      const int xx = rest & 63;
      const int h = rest >> 6;
      const int t = xx * 48 + (j >> 6);
      const int e = ((j & 63) << 4) + h;
      vt[o] = vlin[t * DM + e];
    }
  }
}

// ---------------- kernel 3: flash attention (4 j-quarters, KVBLK=128) -------
// Grid 1024: xcd=b&7, rest=b>>3 (0..127): head = xcd + 8*(rest&1),
// qt = (rest>>1)&15, jq = rest>>5 (0..3). i0 = qt*192, j-range jq*768..+768
// = 6 iters of KVBLK=128. 4 waves; wave w owns rows w*48..w*48+47 (3 ct).
// launch_bounds(256,2): proven VGPR-112 codegen; 4 blocks/CU resident.
extern "C" __global__ __launch_bounds__(256, 2) void attn_kernel(
    const _Float16* __restrict__ qh, const _Float16* __restrict__ kh,
    const _Float16* __restrict__ vt,
    _Float16* __restrict__ oPb, float* __restrict__ smlb)
{
  __shared__ _Float16 SH[16384];  // K0|K1|V0|V1, each 64x64 swizzled (8 KB)
  const int tid = threadIdx.x;
  const int w = tid >> 6, l = tid & 63;
  const int li = l & 15, lg = l >> 4;
  const int b = blockIdx.x;
  const int rest = b >> 3;
  const int head = (b & 7) + 8 * (rest & 1);
  const int qt = (rest >> 1) & 15;
  const int jq = rest >> 5;
  const int i0 = qt * 192;
  const size_t hb = (size_t)head * TSEQ * XD;
  _Float16* oPart = oPb + (size_t)jq * TSEQ * DM;
  float* smlp = smlb + (size_t)jq * TSEQ * NH;

  v8h qf[3][2];
#pragma unroll
  for (int ct = 0; ct < 3; ++ct) {
    const _Float16* qrow = qh + hb + (size_t)(i0 + w * 48 + ct * 16 + li) * XD;
    qf[ct][0] = *(const v8h*)(qrow + lg * 8);
    qf[ct][1] = *(const v8h*)(qrow + 32 + lg * 8);
  }
  float m2[3] = {24.0f * LOG2E, 24.0f * LOG2E, 24.0f * LOG2E};
  float l4[3] = {0.0f, 0.0f, 0.0f};
  v4f oacc[4][3] = {};
  const int r8 = l >> 3, c8 = l & 7;
  const int jbase = jq * 768;

  for (int j0 = jbase; j0 < jbase + 768; j0 += 128) {
    // stage both subtiles: wave w stages 4 chunks per subtile (2 K + 2 V)
#pragma unroll
    for (int s2 = 0; s2 < 2; ++s2) {
      const int jt = j0 + s2 * 64;
#pragma unroll
      for (int s = 0; s < 2; ++s) {
        const int n = w * 2 + s;
        const int row = n * 8 + r8;
        async_load16(kh + hb + (size_t)(jt + row) * XD + ((c8 ^ (row & 7)) * 8),
                     &SH[s2 * 4096 + n * 512]);
        async_load16(vt + hb + (size_t)row * TSEQ + jt + ((c8 ^ (row & 7)) * 8),
                     &SH[8192 + s2 * 4096 + n * 512]);
      }
    }
    __syncthreads();

#pragma unroll
    for (int s2 = 0; s2 < 2; ++s2) {
      const _Float16* Kc = &SH[s2 * 4096];
      const _Float16* Vc = &SH[8192 + s2 * 4096];

      // QK^T: e4[ct][kt] = E^T[j=kt*16+lg*4+r][i=li] - m2[ct]
      v4f e4[3][4];
#pragma unroll
      for (int kt = 0; kt < 4; ++kt) {
        const int krow = kt * 16 + li;
        const v8h kf0 = *(const v8h*)&Kc[krow * 64 + ((lg ^ (li & 7)) * 8)];
        const v8h kf1 = *(const v8h*)&Kc[krow * 64 + (((4 + lg) ^ (li & 7)) * 8)];
#pragma unroll
        for (int ct = 0; ct < 3; ++ct) {
          v4f a = {-m2[ct], -m2[ct], -m2[ct], -m2[ct]};
          a = __builtin_amdgcn_mfma_f32_16x16x32_f16(kf0, qf[ct][0], a, 0, 0, 0);
          a = __builtin_amdgcn_mfma_f32_16x16x32_f16(kf1, qf[ct][1], a, 0, 0, 0);
          e4[ct][kt] = a;
        }
      }

      // guard before exp (e4 already relative to m2)
      float gm = -1.0e30f;
#pragma unroll
      for (int ct = 0; ct < 3; ++ct)
#pragma unroll
        for (int kt = 0; kt < 4; ++kt)
          gm = fmaxf(fmaxf(gm, fmaxf(e4[ct][kt][0], e4[ct][kt][1])),
                     fmaxf(e4[ct][kt][2], e4[ct][kt][3]));
      if (__any(gm > 11.5f)) {            // rare rescale path
#pragma unroll
        for (int ct = 0; ct < 3; ++ct) {
          float rm = -1.0e30f;
#pragma unroll
          for (int kt = 0; kt < 4; ++kt)
            rm = fmaxf(fmaxf(rm, fmaxf(e4[ct][kt][0], e4[ct][kt][1])),
                       fmaxf(e4[ct][kt][2], e4[ct][kt][3]));
          rm = fmaxf(rm, __shfl_xor(rm, 16, 64));
          rm = fmaxf(rm, __shfl_xor(rm, 32, 64));
          rm = fmaxf(rm, 0.0f);
          const float fs = fexp2(-rm);
#pragma unroll
          for (int kt = 0; kt < 4; ++kt)
#pragma unroll
            for (int rr = 0; rr < 4; ++rr) e4[ct][kt][rr] -= rm;
          l4[ct] *= fs;
#pragma unroll
          for (int mi = 0; mi < 4; ++mi) oacc[mi][ct] *= fs;
          m2[ct] += rm;
        }
      }

      // single exp pass -> packed fp16 P + row-sum
      v4h pv[3][4];
#pragma unroll
      for (int ct = 0; ct < 3; ++ct) {
#pragma unroll
        for (int kt = 0; kt < 4; ++kt) {
          const float p0 = fexp2(e4[ct][kt][0]);
          const float p1 = fexp2(e4[ct][kt][1]);
          const float p2 = fexp2(e4[ct][kt][2]);
          const float p3 = fexp2(e4[ct][kt][3]);
          const v2pk lo = __builtin_amdgcn_cvt_pkrtz(p0, p1);
          const v2pk hi = __builtin_amdgcn_cvt_pkrtz(p2, p3);
          const v4pk pk = __builtin_shufflevector(lo, hi, 0, 1, 2, 3);
          pv[ct][kt] = __builtin_bit_cast(v4h, pk);
          l4[ct] += (p0 + p1) + (p2 + p3);
        }
      }

      // PV: each vf read feeds all 3 ct accumulators
#pragma unroll
      for (int mi = 0; mi < 4; ++mi) {
        const int vrow = mi * 16 + li;
        const int vb = vrow * 64 + (lg & 1) * 4;
#pragma unroll
        for (int kt = 0; kt < 4; ++kt) {
          const v4h vf = *(const v4h*)&Vc[vb + (((kt * 2 + (lg >> 1)) ^ (li & 7)) * 8)];
#pragma unroll
          for (int ct = 0; ct < 3; ++ct)
            oacc[mi][ct] = __builtin_amdgcn_mfma_f32_16x16x16f16(
                vf, pv[ct][kt], oacc[mi][ct], 0, 0, 0);
        }
      }
    }
    __syncthreads();
  }

  // ---- finalize: per-wave normalized partial + log-sum (no block merge) ----
#pragma unroll
  for (int ct = 0; ct < 3; ++ct) {
    float ls = l4[ct];
    ls += __shfl_xor(ls, 16, 64);
    ls += __shfl_xor(ls, 32, 64);
    const float inv = 1.0f / ls;
    const int rl = w * 48 + ct * 16 + li;
    if (lg == 0) smlp[(size_t)(i0 + rl) * NH + head] = m2[ct] + flog2(ls);
#pragma unroll
    for (int mi = 0; mi < 4; ++mi) {
      v4h o4;
#pragma unroll
      for (int rr = 0; rr < 4; ++rr) o4[rr] = (_Float16)(oacc[mi][ct][rr] * inv);
      *(v4h*)&oPart[(size_t)(i0 + rl) * DM + head * 64 + mi * 16 + lg * 4] = o4;
    }
  }
}

// ---------------- kernel 4: epilogue (4-way merge + transpose + residual) ---
extern "C" __global__ __launch_bounds__(256) void epilogue_kernel(
    const _Float16* __restrict__ oPb, const float* __restrict__ smlb,
    const float* __restrict__ xin, const float* __restrict__ gscal,
    float* __restrict__ outp)
{
  __shared__ float po[8 * 1024];   // 32 KB fp32 merged [row][h*64+x]
  const int tid = threadIdx.x;
  const size_t t0 = (size_t)blockIdx.x * 8;
  {
    const int tr = tid >> 5;
    const int c0 = (tid & 31) * 32;      // within one head's 64-col block
    const int h = c0 >> 6;
    const size_t t = t0 + tr;
    float s[4], u[4];
#pragma unroll
    for (int q = 0; q < 4; ++q) s[q] = smlb[(size_t)q * TSEQ * NH + t * NH + h];
    const float M = fmaxf(fmaxf(s[0], s[1]), fmaxf(s[2], s[3]));
    float usum = 0.0f;
#pragma unroll
    for (int q = 0; q < 4; ++q) { u[q] = fexp2(s[q] - M); usum += u[q]; }
    const float dn = 1.0f / usum;
#pragma unroll
    for (int q = 0; q < 4; ++q) u[q] *= dn;
#pragma unroll
    for (int c = 0; c < 4; ++c) {
      float acc[8] = {};
#pragma unroll
      for (int q = 0; q < 4; ++q) {
        const v8h a = *(const v8h*)(oPb + (size_t)q * TSEQ * DM + t * DM + c0 + c * 8);
#pragma unroll
        for (int e = 0; e < 8; ++e) acc[e] += u[q] * (float)a[e];
      }
      float4 w0 = {acc[0], acc[1], acc[2], acc[3]};
      float4 w1 = {acc[4], acc[5], acc[6], acc[7]};
      *(float4*)&po[tr * 1024 + c0 + c * 8]     = w0;
      *(float4*)&po[tr * 1024 + c0 + c * 8 + 4] = w1;
    }
  }
  __syncthreads();
  const float g = gscal[0];
  const int tr = tid >> 5;
  const int d0 = (tid & 31) * 32;
  const size_t rb = (t0 + tr) * DM + d0;
#pragma unroll
  for (int c4 = 0; c4 < 8; ++c4) {
    const float4 xi = *(const float4*)&xin[rb + c4 * 4];
    float4 rr;
    rr.x = g * po[tr * 1024 + ((c4 * 4 + 0) & 15) * 64 + ((d0 + c4 * 4 + 0) >> 4)] + xi.x;
    rr.y = g * po[tr * 1024 + ((c4 * 4 + 1) & 15) * 64 + ((d0 + c4 * 4 + 1) >> 4)] + xi.y;
    rr.z = g * po[tr * 1024 + ((c4 * 4 + 2) & 15) * 64 + ((d0 + c4 * 4 + 2) >> 4)] + xi.z;
    rr.w = g * po[tr * 1024 + ((c4 * 4 + 3) & 15) * 64 + ((d0 + c4 * 4 + 3) >> 4)] + xi.w;
    *(float4*)&outp[rb + c4 * 4] = rr;
  }
}

extern "C" void kernel_launch(void* const* d_in, const int* in_sizes, int n_in,
                              void* d_out, int out_size, void* d_ws, size_t ws_size,
                              hipStream_t stream)
{
  const float* x  = (const float*)d_in[0];
  const float* Wq = (const float*)d_in[1];
  const float* bq = (const float*)d_in[2];
  const float* Wk = (const float*)d_in[3];
  const float* bk = (const float*)d_in[4];
  const float* Wv = (const float*)d_in[5];
  const float* bv = (const float*)d_in[6];
  const float* gm = (const float*)d_in[7];
  float* outp = (float*)d_out;
  char* ws = (char*)d_ws;
  const size_t SZH = (size_t)TSEQ * DM * sizeof(_Float16);   // 6 MB
  _Float16* xb   = (_Float16*)(ws);                 // [0,6)   dead after gemm
  _Float16* wb   = (_Float16*)(ws + SZH);           // [6,12)  dead after gemm
  _Float16* qlin = (_Float16*)(ws + 2 * SZH);       // [12,18) dead after repack
  _Float16* klin = (_Float16*)(ws + 3 * SZH);       // [18,24) dead after repack
  _Float16* vlin = (_Float16*)(ws + 4 * SZH);       // [24,30) dead after repack
  _Float16* qhp  = (_Float16*)(ws + 5 * SZH);       // [30,36)
  _Float16* khp  = (_Float16*)(ws + 6 * SZH);       // [36,42)
  _Float16* vtp  = (_Float16*)(ws + 7 * SZH);       // [42,48)
  _Float16* oPb  = (_Float16*)(ws);                 // 4 x 6MB: reuses [0,24)
  float*    smlb = (float*)(ws + 4 * SZH);          // 4 x 192KB: reuses vlin

  cvt_kernel<<<dim3(2048), dim3(256), 0, stream>>>(x, Wq, Wk, Wv, xb, wb);
  qkv_gemm_kernel<<<dim3(576), dim3(256), 0, stream>>>(xb, wb, bq, bk, bv,
                                                       qlin, klin, vlin);
  repack_kernel<<<dim3(4096), dim3(256), 0, stream>>>(qlin, klin, vlin,
                                                      qhp, khp, vtp);
  attn_kernel<<<dim3(1024), dim3(256), 0, stream>>>(qhp, khp, vtp, oPb, smlb);
  epilogue_kernel<<<dim3(384), dim3(256), 0, stream>>>(oPb, smlb, x, gm, outp);
  (void)in_sizes; (void)n_in; (void)out_size; (void)ws_size;
}

// Round 21
// 133.597 us; speedup vs baseline: 1.0282x; 1.0282x over previous
//
#include <hip/hip_runtime.h>

// MultiHeadAttention (SAGAN reshape), B=C=1, T=3072, D=1024, H=16, head-dim 64.
// Round 21 = exact restore of R19 (verified best: 132.9us; attn 65.3).
// Session summary: fp16-MFMA pipeline (cvt -> fused QKV GEMM -> repack ->
// flash attn [KVBLK=128, j-half across blocks, deferred-max log2-domain
// softmax, in-register P] -> merge epilogue). All further levers tested
// R5-R20 (volume, cache tier, pipelining, occupancy, TLP, barrier count,
// pipe rebalancing) were null or negative; attn is latency-chain-bound at
// ~35% MfmaUtil with no saturated pipe.

typedef _Float16 v8h __attribute__((ext_vector_type(8)));
typedef _Float16 v4h __attribute__((ext_vector_type(4)));
typedef __fp16   v2pk __attribute__((ext_vector_type(2)));
typedef __fp16   v4pk __attribute__((ext_vector_type(4)));
typedef float    v4f __attribute__((ext_vector_type(4)));

#define TSEQ 3072
#define DM   1024
#define NH   16
#define XD   64
#define LOG2E 1.44269504f

__device__ __forceinline__ void async_load16(const void* g, void* l) {
  __builtin_amdgcn_global_load_lds(
      (const __attribute__((address_space(1))) unsigned int*)g,
      (__attribute__((address_space(3))) unsigned int*)l,
      16, 0, 0);
}

__device__ __forceinline__ float fexp2(float x) {
  float r; asm("v_exp_f32 %0, %1" : "=v"(r) : "v"(x)); return r;
}
__device__ __forceinline__ float flog2(float x) {
  float r; asm("v_log_f32 %0, %1" : "=v"(r) : "v"(x)); return r;
}

// ---------------- kernel 0: fp32 -> fp16 conversion -------------------------
extern "C" __global__ __launch_bounds__(256) void cvt_kernel(
    const float* __restrict__ x, const float* __restrict__ wq,
    const float* __restrict__ wk, const float* __restrict__ wv,
    _Float16* __restrict__ xb, _Float16* __restrict__ wb)
{
  const int NX4 = (TSEQ * DM) / 4;
  const int NT  = NX4 * 2;
  for (int i = blockIdx.x * blockDim.x + threadIdx.x; i < NT;
       i += gridDim.x * blockDim.x) {
    float4 v;
    _Float16* dst;
    if (i < NX4) {
      v = ((const float4*)x)[i];
      dst = xb + (size_t)i * 4;
    } else {
      const int j = i - NX4;
      const int n = j >> 8;
      if (n < 1024)      v = ((const float4*)wq)[j];
      else if (n < 2048) v = ((const float4*)wk)[j - 262144];
      else               v = ((const float4*)wv)[j - 524288];
      dst = wb + (size_t)j * 4;
    }
    v4h h;
    h[0] = (_Float16)v.x; h[1] = (_Float16)v.y;
    h[2] = (_Float16)v.z; h[3] = (_Float16)v.w;
    *(v4h*)dst = h;
  }
}

// ---------------- kernel 1: fused QKV GEMM (BK=32, row-major epilogue) ------
extern "C" __global__ __launch_bounds__(256) void qkv_gemm_kernel(
    const _Float16* __restrict__ xb, const _Float16* __restrict__ wb,
    const float* __restrict__ bq, const float* __restrict__ bk,
    const float* __restrict__ bv,
    _Float16* __restrict__ qlin, _Float16* __restrict__ klin,
    _Float16* __restrict__ vlin)
{
  __shared__ _Float16 As[128 * 32];
  __shared__ _Float16 Bs[128 * 32];
  const int tid = threadIdx.x;
  const int w = tid >> 6, l = tid & 63;
  const int li = l & 15, lg = l >> 4;
  const int wm = w >> 1, wn = w & 1;
  const int bid = blockIdx.x;                 // 576 = 72*8, bijective XCD swz
  const int swz = (bid & 7) * 72 + (bid >> 3);
  const int m0 = (swz / 24) * 128, n0 = (swz % 24) * 128;
  v4f acc[4][4] = {};
  const int srow = l >> 2;
  const int scol = (l & 3) * 8;
  for (int k0 = 0; k0 < DM; k0 += 32) {
#pragma unroll
    for (int c = 0; c < 2; ++c) {
      const int rbase = c * 64 + w * 16;
      async_load16(xb + (size_t)(m0 + rbase + srow) * DM + k0 + scol, &As[rbase * 32]);
      async_load16(wb + (size_t)(n0 + rbase + srow) * DM + k0 + scol, &Bs[rbase * 32]);
    }
    __syncthreads();
    v8h af[4], bf[4];
#pragma unroll
    for (int mi = 0; mi < 4; ++mi)
      af[mi] = *(const v8h*)&As[(wm * 64 + mi * 16 + li) * 32 + lg * 8];
#pragma unroll
    for (int ni = 0; ni < 4; ++ni)
      bf[ni] = *(const v8h*)&Bs[(wn * 64 + ni * 16 + li) * 32 + lg * 8];
#pragma unroll
    for (int mi = 0; mi < 4; ++mi)
#pragma unroll
      for (int ni = 0; ni < 4; ++ni)
        acc[mi][ni] = __builtin_amdgcn_mfma_f32_16x16x32_f16(
            af[mi], bf[ni], acc[mi][ni], 0, 0, 0);
    __syncthreads();
  }
  const int which = n0 >> 10;
  const int ebase = n0 & 1023;
  const float* bias = which == 0 ? bq : (which == 1 ? bk : bv);
  _Float16* outp = which == 0 ? qlin : (which == 1 ? klin : vlin);
#pragma unroll
  for (int mi = 0; mi < 4; ++mi)
#pragma unroll
    for (int r = 0; r < 4; ++r) {
      const int t = m0 + wm * 64 + mi * 16 + lg * 4 + r;
#pragma unroll
      for (int ni = 0; ni < 4; ++ni) {
        const int e = ebase + wn * 64 + ni * 16 + li;
        outp[(size_t)t * DM + e] = (_Float16)(acc[mi][ni][r] + bias[e]);
      }
    }
}

// ---------------- kernel 2: per-head repack ---------------------------------
extern "C" __global__ __launch_bounds__(256) void repack_kernel(
    const _Float16* __restrict__ qlin, const _Float16* __restrict__ klin,
    const _Float16* __restrict__ vlin,
    _Float16* __restrict__ qh, _Float16* __restrict__ kh,
    _Float16* __restrict__ vt)
{
  const int NE = NH * TSEQ * XD;   // 3145728
  for (int g = blockIdx.x * blockDim.x + threadIdx.x; g < 3 * NE;
       g += gridDim.x * blockDim.x) {
    if (g < 2 * NE) {
      const int gg = (g < NE) ? g : g - NE;
      const int xx = gg & 63;
      const int rest = gg >> 6;          // h*3072 + i
      const int h = rest / TSEQ;
      const int i = rest - h * TSEQ;
      const int t = xx * 48 + (i >> 6);
      const int e = ((i & 63) << 4) + h;
      if (g < NE) qh[gg] = qlin[t * DM + e];
      else        kh[gg] = (_Float16)((float)klin[t * DM + e] * LOG2E);
    } else {
      const int o = g - 2 * NE;
      const int j = o % TSEQ;
      const int rest = o / TSEQ;          // h*64 + x
      const int xx = rest & 63;
      const int h = rest >> 6;
      const int t = xx * 48 + (j >> 6);
      const int e = ((j & 63) << 4) + h;
      vt[o] = vlin[t * DM + e];
    }
  }
}

// ---------------- kernel 3: flash attention (KVBLK=128, 12 barrier pairs) ---
// Grid 512: xcd=b&7, rest=b>>3 (0..63): head = xcd + 8*(rest&1),
// qt = (rest>>1)&15, jh = rest>>5. i0 = qt*192. 4 waves; wave w owns rows
// w*48..w*48+47 (3 ct). Per iter: stage TWO 64-j subtiles (32 KB), one
// barrier, compute both, one barrier.
extern "C" __global__ __launch_bounds__(256, 2) void attn_kernel(
    const _Float16* __restrict__ qh, const _Float16* __restrict__ kh,
    const _Float16* __restrict__ vt,
    _Float16* __restrict__ oP0, _Float16* __restrict__ oP1,
    float* __restrict__ sml0, float* __restrict__ sml1)
{
  __shared__ _Float16 SH[16384];  // K0|K1|V0|V1, each 64x64 swizzled (8 KB)
  const int tid = threadIdx.x;
  const int w = tid >> 6, l = tid & 63;
  const int li = l & 15, lg = l >> 4;
  const int b = blockIdx.x;
  const int rest = b >> 3;
  const int head = (b & 7) + 8 * (rest & 1);
  const int qt = (rest >> 1) & 15;
  const int jh = rest >> 5;
  const int i0 = qt * 192;
  const size_t hb = (size_t)head * TSEQ * XD;
  _Float16* oPart = jh ? oP1 : oP0;
  float* smlp = jh ? sml1 : sml0;

  v8h qf[3][2];
#pragma unroll
  for (int ct = 0; ct < 3; ++ct) {
    const _Float16* qrow = qh + hb + (size_t)(i0 + w * 48 + ct * 16 + li) * XD;
    qf[ct][0] = *(const v8h*)(qrow + lg * 8);
    qf[ct][1] = *(const v8h*)(qrow + 32 + lg * 8);
  }
  float m2[3] = {24.0f * LOG2E, 24.0f * LOG2E, 24.0f * LOG2E};
  float l4[3] = {0.0f, 0.0f, 0.0f};
  v4f oacc[4][3] = {};
  const int r8 = l >> 3, c8 = l & 7;
  const int jbase = jh * 1536;

  for (int j0 = jbase; j0 < jbase + 1536; j0 += 128) {
    // stage both subtiles: wave w stages 4 chunks per subtile (2 K + 2 V)
#pragma unroll
    for (int s2 = 0; s2 < 2; ++s2) {
      const int jt = j0 + s2 * 64;
#pragma unroll
      for (int s = 0; s < 2; ++s) {
        const int n = w * 2 + s;
        const int row = n * 8 + r8;
        async_load16(kh + hb + (size_t)(jt + row) * XD + ((c8 ^ (row & 7)) * 8),
                     &SH[s2 * 4096 + n * 512]);
        async_load16(vt + hb + (size_t)row * TSEQ + jt + ((c8 ^ (row & 7)) * 8),
                     &SH[8192 + s2 * 4096 + n * 512]);
      }
    }
    __syncthreads();

#pragma unroll
    for (int s2 = 0; s2 < 2; ++s2) {
      const _Float16* Kc = &SH[s2 * 4096];
      const _Float16* Vc = &SH[8192 + s2 * 4096];

      // QK^T: e4[ct][kt] = E^T[j=kt*16+lg*4+r][i=li] - m2[ct]
      v4f e4[3][4];
#pragma unroll
      for (int kt = 0; kt < 4; ++kt) {
        const int krow = kt * 16 + li;
        const v8h kf0 = *(const v8h*)&Kc[krow * 64 + ((lg ^ (li & 7)) * 8)];
        const v8h kf1 = *(const v8h*)&Kc[krow * 64 + (((4 + lg) ^ (li & 7)) * 8)];
#pragma unroll
        for (int ct = 0; ct < 3; ++ct) {
          v4f a = {-m2[ct], -m2[ct], -m2[ct], -m2[ct]};
          a = __builtin_amdgcn_mfma_f32_16x16x32_f16(kf0, qf[ct][0], a, 0, 0, 0);
          a = __builtin_amdgcn_mfma_f32_16x16x32_f16(kf1, qf[ct][1], a, 0, 0, 0);
          e4[ct][kt] = a;
        }
      }

      // guard before exp (e4 already relative to m2)
      float gm = -1.0e30f;
#pragma unroll
      for (int ct = 0; ct < 3; ++ct)
#pragma unroll
        for (int kt = 0; kt < 4; ++kt)
          gm = fmaxf(fmaxf(gm, fmaxf(e4[ct][kt][0], e4[ct][kt][1])),
                     fmaxf(e4[ct][kt][2], e4[ct][kt][3]));
      if (__any(gm > 11.5f)) {            // rare rescale path
#pragma unroll
        for (int ct = 0; ct < 3; ++ct) {
          float rm = -1.0e30f;
#pragma unroll
          for (int kt = 0; kt < 4; ++kt)
            rm = fmaxf(fmaxf(rm, fmaxf(e4[ct][kt][0], e4[ct][kt][1])),
                       fmaxf(e4[ct][kt][2], e4[ct][kt][3]));
          rm = fmaxf(rm, __shfl_xor(rm, 16, 64));
          rm = fmaxf(rm, __shfl_xor(rm, 32, 64));
          rm = fmaxf(rm, 0.0f);
          const float fs = fexp2(-rm);
#pragma unroll
          for (int kt = 0; kt < 4; ++kt)
#pragma unroll
            for (int rr = 0; rr < 4; ++rr) e4[ct][kt][rr] -= rm;
          l4[ct] *= fs;
#pragma unroll
          for (int mi = 0; mi < 4; ++mi) oacc[mi][ct] *= fs;
          m2[ct] += rm;
        }
      }

      // single exp pass -> packed fp16 P + row-sum
      v4h pv[3][4];
#pragma unroll
      for (int ct = 0; ct < 3; ++ct) {
#pragma unroll
        for (int kt = 0; kt < 4; ++kt) {
          const float p0 = fexp2(e4[ct][kt][0]);
          const float p1 = fexp2(e4[ct][kt][1]);
          const float p2 = fexp2(e4[ct][kt][2]);
          const float p3 = fexp2(e4[ct][kt][3]);
          const v2pk lo = __builtin_amdgcn_cvt_pkrtz(p0, p1);
          const v2pk hi = __builtin_amdgcn_cvt_pkrtz(p2, p3);
          const v4pk pk = __builtin_shufflevector(lo, hi, 0, 1, 2, 3);
          pv[ct][kt] = __builtin_bit_cast(v4h, pk);
          l4[ct] += (p0 + p1) + (p2 + p3);
        }
      }

      // PV: each vf read feeds all 3 ct accumulators
#pragma unroll
      for (int mi = 0; mi < 4; ++mi) {
        const int vrow = mi * 16 + li;
        const int vb = vrow * 64 + (lg & 1) * 4;
#pragma unroll
        for (int kt = 0; kt < 4; ++kt) {
          const v4h vf = *(const v4h*)&Vc[vb + (((kt * 2 + (lg >> 1)) ^ (li & 7)) * 8)];
#pragma unroll
          for (int ct = 0; ct < 3; ++ct)
            oacc[mi][ct] = __builtin_amdgcn_mfma_f32_16x16x16f16(
                vf, pv[ct][kt], oacc[mi][ct], 0, 0, 0);
        }
      }
    }
    __syncthreads();
  }

  // ---- finalize: per-wave normalized partial + log-sum (no block merge) ----
#pragma unroll
  for (int ct = 0; ct < 3; ++ct) {
    float ls = l4[ct];
    ls += __shfl_xor(ls, 16, 64);
    ls += __shfl_xor(ls, 32, 64);
    const float inv = 1.0f / ls;
    const int rl = w * 48 + ct * 16 + li;
    if (lg == 0) smlp[(size_t)(i0 + rl) * NH + head] = m2[ct] + flog2(ls);
#pragma unroll
    for (int mi = 0; mi < 4; ++mi) {
      v4h o4;
#pragma unroll
      for (int rr = 0; rr < 4; ++rr) o4[rr] = (_Float16)(oacc[mi][ct][rr] * inv);
      *(v4h*)&oPart[(size_t)(i0 + rl) * DM + head * 64 + mi * 16 + lg * 4] = o4;
    }
  }
}

// ---------------- kernel 4: epilogue (j-half merge + transpose + residual) --
extern "C" __global__ __launch_bounds__(256) void epilogue_kernel(
    const _Float16* __restrict__ oP0, const _Float16* __restrict__ oP1,
    const float* __restrict__ sml0, const float* __restrict__ sml1,
    const float* __restrict__ xin, const float* __restrict__ gscal,
    float* __restrict__ outp)
{
  __shared__ float po[8 * 1024];   // 32 KB fp32 merged [row][h*64+x]
  const int tid = threadIdx.x;
  const size_t t0 = (size_t)blockIdx.x * 8;
  {
    const int tr = tid >> 5;
    const int c0 = (tid & 31) * 32;      // within one head's 64-col block
    const int h = c0 >> 6;
    const size_t t = t0 + tr;
    const float s0 = sml0[t * NH + h], s1 = sml1[t * NH + h];
    const float M = fmaxf(s0, s1);
    float u0 = fexp2(s0 - M), u1 = fexp2(s1 - M);
    const float dn = 1.0f / (u0 + u1);
    u0 *= dn; u1 *= dn;
    const _Float16* p0 = oP0 + t * DM + c0;
    const _Float16* p1 = oP1 + t * DM + c0;
#pragma unroll
    for (int c = 0; c < 4; ++c) {
      const v8h a = *(const v8h*)(p0 + c * 8);
      const v8h bb = *(const v8h*)(p1 + c * 8);
      float acc[8];
#pragma unroll
      for (int e = 0; e < 8; ++e)
        acc[e] = u0 * (float)a[e] + u1 * (float)bb[e];
      float4 w0 = {acc[0], acc[1], acc[2], acc[3]};
      float4 w1 = {acc[4], acc[5], acc[6], acc[7]};
      *(float4*)&po[tr * 1024 + c0 + c * 8]     = w0;
      *(float4*)&po[tr * 1024 + c0 + c * 8 + 4] = w1;
    }
  }
  __syncthreads();
  const float g = gscal[0];
  const int tr = tid >> 5;
  const int d0 = (tid & 31) * 32;
  const size_t rb = (t0 + tr) * DM + d0;
#pragma unroll
  for (int c4 = 0; c4 < 8; ++c4) {
    const float4 xi = *(const float4*)&xin[rb + c4 * 4];
    float4 rr;
    rr.x = g * po[tr * 1024 + ((c4 * 4 + 0) & 15) * 64 + ((d0 + c4 * 4 + 0) >> 4)] + xi.x;
    rr.y = g * po[tr * 1024 + ((c4 * 4 + 1) & 15) * 64 + ((d0 + c4 * 4 + 1) >> 4)] + xi.y;
    rr.z = g * po[tr * 1024 + ((c4 * 4 + 2) & 15) * 64 + ((d0 + c4 * 4 + 2) >> 4)] + xi.z;
    rr.w = g * po[tr * 1024 + ((c4 * 4 + 3) & 15) * 64 + ((d0 + c4 * 4 + 3) >> 4)] + xi.w;
    *(float4*)&outp[rb + c4 * 4] = rr;
  }
}

extern "C" void kernel_launch(void* const* d_in, const int* in_sizes, int n_in,
                              void* d_out, int out_size, void* d_ws, size_t ws_size,
                              hipStream_t stream)
{
  const float* x  = (const float*)d_in[0];
  const float* Wq = (const float*)d_in[1];
  const float* bq = (const float*)d_in[2];
  const float* Wk = (const float*)d_in[3];
  const float* bk = (const float*)d_in[4];
  const float* Wv = (const float*)d_in[5];
  const float* bv = (const float*)d_in[6];
  const float* gm = (const float*)d_in[7];
  float* outp = (float*)d_out;
  char* ws = (char*)d_ws;
  const size_t SZH = (size_t)TSEQ * DM * sizeof(_Float16);   // 6 MB
  _Float16* xb   = (_Float16*)(ws);                 // [0,6)   dead after gemm
  _Float16* wb   = (_Float16*)(ws + SZH);           // [6,12)  dead after gemm
  _Float16* qlin = (_Float16*)(ws + 2 * SZH);       // [12,18)
  _Float16* klin = (_Float16*)(ws + 3 * SZH);       // [18,24) dead after repack
  _Float16* vlin = (_Float16*)(ws + 4 * SZH);       // [24,30)
  _Float16* qhp  = (_Float16*)(ws + 5 * SZH);       // [30,36)
  _Float16* khp  = (_Float16*)(ws + 6 * SZH);       // [36,42)
  _Float16* vtp  = (_Float16*)(ws + 7 * SZH);       // [42,48)
  _Float16* oP0  = (_Float16*)(ws);                 // reuses [0,6)  (xb dead)
  _Float16* oP1  = (_Float16*)(ws + SZH);           // reuses [6,12) (wb dead)
  float*    sml0 = (float*)(ws + 3 * SZH);          // reuses klin (dead)
  float*    sml1 = sml0 + (size_t)TSEQ * NH;

  cvt_kernel<<<dim3(2048), dim3(256), 0, stream>>>(x, Wq, Wk, Wv, xb, wb);
  qkv_gemm_kernel<<<dim3(576), dim3(256), 0, stream>>>(xb, wb, bq, bk, bv,
                                                       qlin, klin, vlin);
  repack_kernel<<<dim3(4096), dim3(256), 0, stream>>>(qlin, klin, vlin,
                                                      qhp, khp, vtp);
  attn_kernel<<<dim3(512), dim3(256), 0, stream>>>(qhp, khp, vtp,
                                                   oP0, oP1, sml0, sml1);
  epilogue_kernel<<<dim3(384), dim3(256), 0, stream>>>(oP0, oP1, sml0, sml1,
                                                       x, gm, outp);
  (void)in_sizes; (void)n_in; (void)out_size; (void)ws_size;
}

// Round 22
// 132.373 us; speedup vs baseline: 1.0377x; 1.0092x over previous
//
#include <hip/hip_runtime.h>

// MultiHeadAttention (SAGAN reshape), B=C=1, T=3072, D=1024, H=16, head-dim 64.
// Round 22 = R21 with ONE attn change: single guard per 128-j tile (math-
// equivalent online softmax over the combined tile), then a branch-free
// exp(0) -> PV(0) -> exp(1) -> PV(1) region so the scheduler can interleave
// exp(1) VALU with PV(0) MFMA (T15-style within-wave pipe overlap).

typedef _Float16 v8h __attribute__((ext_vector_type(8)));
typedef _Float16 v4h __attribute__((ext_vector_type(4)));
typedef __fp16   v2pk __attribute__((ext_vector_type(2)));
typedef __fp16   v4pk __attribute__((ext_vector_type(4)));
typedef float    v4f __attribute__((ext_vector_type(4)));

#define TSEQ 3072
#define DM   1024
#define NH   16
#define XD   64
#define LOG2E 1.44269504f

__device__ __forceinline__ void async_load16(const void* g, void* l) {
  __builtin_amdgcn_global_load_lds(
      (const __attribute__((address_space(1))) unsigned int*)g,
      (__attribute__((address_space(3))) unsigned int*)l,
      16, 0, 0);
}

__device__ __forceinline__ float fexp2(float x) {
  float r; asm("v_exp_f32 %0, %1" : "=v"(r) : "v"(x)); return r;
}
__device__ __forceinline__ float flog2(float x) {
  float r; asm("v_log_f32 %0, %1" : "=v"(r) : "v"(x)); return r;
}

// ---------------- kernel 0: fp32 -> fp16 conversion -------------------------
extern "C" __global__ __launch_bounds__(256) void cvt_kernel(
    const float* __restrict__ x, const float* __restrict__ wq,
    const float* __restrict__ wk, const float* __restrict__ wv,
    _Float16* __restrict__ xb, _Float16* __restrict__ wb)
{
  const int NX4 = (TSEQ * DM) / 4;
  const int NT  = NX4 * 2;
  for (int i = blockIdx.x * blockDim.x + threadIdx.x; i < NT;
       i += gridDim.x * blockDim.x) {
    float4 v;
    _Float16* dst;
    if (i < NX4) {
      v = ((const float4*)x)[i];
      dst = xb + (size_t)i * 4;
    } else {
      const int j = i - NX4;
      const int n = j >> 8;
      if (n < 1024)      v = ((const float4*)wq)[j];
      else if (n < 2048) v = ((const float4*)wk)[j - 262144];
      else               v = ((const float4*)wv)[j - 524288];
      dst = wb + (size_t)j * 4;
    }
    v4h h;
    h[0] = (_Float16)v.x; h[1] = (_Float16)v.y;
    h[2] = (_Float16)v.z; h[3] = (_Float16)v.w;
    *(v4h*)dst = h;
  }
}

// ---------------- kernel 1: fused QKV GEMM (BK=32, row-major epilogue) ------
extern "C" __global__ __launch_bounds__(256) void qkv_gemm_kernel(
    const _Float16* __restrict__ xb, const _Float16* __restrict__ wb,
    const float* __restrict__ bq, const float* __restrict__ bk,
    const float* __restrict__ bv,
    _Float16* __restrict__ qlin, _Float16* __restrict__ klin,
    _Float16* __restrict__ vlin)
{
  __shared__ _Float16 As[128 * 32];
  __shared__ _Float16 Bs[128 * 32];
  const int tid = threadIdx.x;
  const int w = tid >> 6, l = tid & 63;
  const int li = l & 15, lg = l >> 4;
  const int wm = w >> 1, wn = w & 1;
  const int bid = blockIdx.x;                 // 576 = 72*8, bijective XCD swz
  const int swz = (bid & 7) * 72 + (bid >> 3);
  const int m0 = (swz / 24) * 128, n0 = (swz % 24) * 128;
  v4f acc[4][4] = {};
  const int srow = l >> 2;
  const int scol = (l & 3) * 8;
  for (int k0 = 0; k0 < DM; k0 += 32) {
#pragma unroll
    for (int c = 0; c < 2; ++c) {
      const int rbase = c * 64 + w * 16;
      async_load16(xb + (size_t)(m0 + rbase + srow) * DM + k0 + scol, &As[rbase * 32]);
      async_load16(wb + (size_t)(n0 + rbase + srow) * DM + k0 + scol, &Bs[rbase * 32]);
    }
    __syncthreads();
    v8h af[4], bf[4];
#pragma unroll
    for (int mi = 0; mi < 4; ++mi)
      af[mi] = *(const v8h*)&As[(wm * 64 + mi * 16 + li) * 32 + lg * 8];
#pragma unroll
    for (int ni = 0; ni < 4; ++ni)
      bf[ni] = *(const v8h*)&Bs[(wn * 64 + ni * 16 + li) * 32 + lg * 8];
#pragma unroll
    for (int mi = 0; mi < 4; ++mi)
#pragma unroll
      for (int ni = 0; ni < 4; ++ni)
        acc[mi][ni] = __builtin_amdgcn_mfma_f32_16x16x32_f16(
            af[mi], bf[ni], acc[mi][ni], 0, 0, 0);
    __syncthreads();
  }
  const int which = n0 >> 10;
  const int ebase = n0 & 1023;
  const float* bias = which == 0 ? bq : (which == 1 ? bk : bv);
  _Float16* outp = which == 0 ? qlin : (which == 1 ? klin : vlin);
#pragma unroll
  for (int mi = 0; mi < 4; ++mi)
#pragma unroll
    for (int r = 0; r < 4; ++r) {
      const int t = m0 + wm * 64 + mi * 16 + lg * 4 + r;
#pragma unroll
      for (int ni = 0; ni < 4; ++ni) {
        const int e = ebase + wn * 64 + ni * 16 + li;
        outp[(size_t)t * DM + e] = (_Float16)(acc[mi][ni][r] + bias[e]);
      }
    }
}

// ---------------- kernel 2: per-head repack ---------------------------------
extern "C" __global__ __launch_bounds__(256) void repack_kernel(
    const _Float16* __restrict__ qlin, const _Float16* __restrict__ klin,
    const _Float16* __restrict__ vlin,
    _Float16* __restrict__ qh, _Float16* __restrict__ kh,
    _Float16* __restrict__ vt)
{
  const int NE = NH * TSEQ * XD;   // 3145728
  for (int g = blockIdx.x * blockDim.x + threadIdx.x; g < 3 * NE;
       g += gridDim.x * blockDim.x) {
    if (g < 2 * NE) {
      const int gg = (g < NE) ? g : g - NE;
      const int xx = gg & 63;
      const int rest = gg >> 6;          // h*3072 + i
      const int h = rest / TSEQ;
      const int i = rest - h * TSEQ;
      const int t = xx * 48 + (i >> 6);
      const int e = ((i & 63) << 4) + h;
      if (g < NE) qh[gg] = qlin[t * DM + e];
      else        kh[gg] = (_Float16)((float)klin[t * DM + e] * LOG2E);
    } else {
      const int o = g - 2 * NE;
      const int j = o % TSEQ;
      const int rest = o / TSEQ;          // h*64 + x
      const int xx = rest & 63;
      const int h = rest >> 6;
      const int t = xx * 48 + (j >> 6);
      const int e = ((j & 63) << 4) + h;
      vt[o] = vlin[t * DM + e];
    }
  }
}

// ---------------- kernel 3: flash attention (merged guard, interleavable) ---
// Grid 512: xcd=b&7, rest=b>>3 (0..63): head = xcd + 8*(rest&1),
// qt = (rest>>1)&15, jh = rest>>5. i0 = qt*192. 4 waves; wave w owns rows
// w*48..w*48+47 (3 ct). Per iter (KVBLK=128): stage both subtiles, barrier,
// QK(0)+QK(1) -> single guard/rescale over the 128-j tile -> branch-free
// exp(0), PV(0), exp(1), PV(1) region -> barrier.
extern "C" __global__ __launch_bounds__(256, 2) void attn_kernel(
    const _Float16* __restrict__ qh, const _Float16* __restrict__ kh,
    const _Float16* __restrict__ vt,
    _Float16* __restrict__ oP0, _Float16* __restrict__ oP1,
    float* __restrict__ sml0, float* __restrict__ sml1)
{
  __shared__ _Float16 SH[16384];  // K0|K1|V0|V1, each 64x64 swizzled (8 KB)
  const int tid = threadIdx.x;
  const int w = tid >> 6, l = tid & 63;
  const int li = l & 15, lg = l >> 4;
  const int b = blockIdx.x;
  const int rest = b >> 3;
  const int head = (b & 7) + 8 * (rest & 1);
  const int qt = (rest >> 1) & 15;
  const int jh = rest >> 5;
  const int i0 = qt * 192;
  const size_t hb = (size_t)head * TSEQ * XD;
  _Float16* oPart = jh ? oP1 : oP0;
  float* smlp = jh ? sml1 : sml0;

  v8h qf[3][2];
#pragma unroll
  for (int ct = 0; ct < 3; ++ct) {
    const _Float16* qrow = qh + hb + (size_t)(i0 + w * 48 + ct * 16 + li) * XD;
    qf[ct][0] = *(const v8h*)(qrow + lg * 8);
    qf[ct][1] = *(const v8h*)(qrow + 32 + lg * 8);
  }
  float m2[3] = {24.0f * LOG2E, 24.0f * LOG2E, 24.0f * LOG2E};
  float l4[3] = {0.0f, 0.0f, 0.0f};
  v4f oacc[4][3] = {};
  const int r8 = l >> 3, c8 = l & 7;
  const int jbase = jh * 1536;

  for (int j0 = jbase; j0 < jbase + 1536; j0 += 128) {
    // stage both subtiles: wave w stages 4 chunks per subtile (2 K + 2 V)
#pragma unroll
    for (int s2 = 0; s2 < 2; ++s2) {
      const int jt = j0 + s2 * 64;
#pragma unroll
      for (int s = 0; s < 2; ++s) {
        const int n = w * 2 + s;
        const int row = n * 8 + r8;
        async_load16(kh + hb + (size_t)(jt + row) * XD + ((c8 ^ (row & 7)) * 8),
                     &SH[s2 * 4096 + n * 512]);
        async_load16(vt + hb + (size_t)row * TSEQ + jt + ((c8 ^ (row & 7)) * 8),
                     &SH[8192 + s2 * 4096 + n * 512]);
      }
    }
    __syncthreads();

    // QK^T for BOTH subtiles: e4[s2][ct][kt] = E^T - m2[ct]
    v4f e4[2][3][4];
#pragma unroll
    for (int s2 = 0; s2 < 2; ++s2) {
      const _Float16* Kc = &SH[s2 * 4096];
#pragma unroll
      for (int kt = 0; kt < 4; ++kt) {
        const int krow = kt * 16 + li;
        const v8h kf0 = *(const v8h*)&Kc[krow * 64 + ((lg ^ (li & 7)) * 8)];
        const v8h kf1 = *(const v8h*)&Kc[krow * 64 + (((4 + lg) ^ (li & 7)) * 8)];
#pragma unroll
        for (int ct = 0; ct < 3; ++ct) {
          v4f a = {-m2[ct], -m2[ct], -m2[ct], -m2[ct]};
          a = __builtin_amdgcn_mfma_f32_16x16x32_f16(kf0, qf[ct][0], a, 0, 0, 0);
          a = __builtin_amdgcn_mfma_f32_16x16x32_f16(kf1, qf[ct][1], a, 0, 0, 0);
          e4[s2][ct][kt] = a;
        }
      }
    }

    // SINGLE guard over the whole 128-j tile
    float gm = -1.0e30f;
#pragma unroll
    for (int s2 = 0; s2 < 2; ++s2)
#pragma unroll
      for (int ct = 0; ct < 3; ++ct)
#pragma unroll
        for (int kt = 0; kt < 4; ++kt)
          gm = fmaxf(fmaxf(gm, fmaxf(e4[s2][ct][kt][0], e4[s2][ct][kt][1])),
                     fmaxf(e4[s2][ct][kt][2], e4[s2][ct][kt][3]));
    if (__any(gm > 11.5f)) {            // rare rescale path (both subtiles)
#pragma unroll
      for (int ct = 0; ct < 3; ++ct) {
        float rm = -1.0e30f;
#pragma unroll
        for (int s2 = 0; s2 < 2; ++s2)
#pragma unroll
          for (int kt = 0; kt < 4; ++kt)
            rm = fmaxf(fmaxf(rm, fmaxf(e4[s2][ct][kt][0], e4[s2][ct][kt][1])),
                       fmaxf(e4[s2][ct][kt][2], e4[s2][ct][kt][3]));
        rm = fmaxf(rm, __shfl_xor(rm, 16, 64));
        rm = fmaxf(rm, __shfl_xor(rm, 32, 64));
        rm = fmaxf(rm, 0.0f);
        const float fs = fexp2(-rm);
#pragma unroll
        for (int s2 = 0; s2 < 2; ++s2)
#pragma unroll
          for (int kt = 0; kt < 4; ++kt)
#pragma unroll
            for (int rr = 0; rr < 4; ++rr) e4[s2][ct][kt][rr] -= rm;
        l4[ct] *= fs;
#pragma unroll
        for (int mi = 0; mi < 4; ++mi) oacc[mi][ct] *= fs;
        m2[ct] += rm;
      }
    }

    // branch-free region: exp(0) -> PV(0) -> exp(1) -> PV(1).
    // exp(1) is independent of PV(0): scheduler may interleave VALU & MFMA.
#pragma unroll
    for (int s2 = 0; s2 < 2; ++s2) {
      const _Float16* Vc = &SH[8192 + s2 * 4096];
      v4h pv[3][4];
#pragma unroll
      for (int ct = 0; ct < 3; ++ct) {
#pragma unroll
        for (int kt = 0; kt < 4; ++kt) {
          const float p0 = fexp2(e4[s2][ct][kt][0]);
          const float p1 = fexp2(e4[s2][ct][kt][1]);
          const float p2 = fexp2(e4[s2][ct][kt][2]);
          const float p3 = fexp2(e4[s2][ct][kt][3]);
          const v2pk lo = __builtin_amdgcn_cvt_pkrtz(p0, p1);
          const v2pk hi = __builtin_amdgcn_cvt_pkrtz(p2, p3);
          const v4pk pk = __builtin_shufflevector(lo, hi, 0, 1, 2, 3);
          pv[ct][kt] = __builtin_bit_cast(v4h, pk);
          l4[ct] += (p0 + p1) + (p2 + p3);
        }
      }
#pragma unroll
      for (int mi = 0; mi < 4; ++mi) {
        const int vrow = mi * 16 + li;
        const int vb = vrow * 64 + (lg & 1) * 4;
#pragma unroll
        for (int kt = 0; kt < 4; ++kt) {
          const v4h vf = *(const v4h*)&Vc[vb + (((kt * 2 + (lg >> 1)) ^ (li & 7)) * 8)];
#pragma unroll
          for (int ct = 0; ct < 3; ++ct)
            oacc[mi][ct] = __builtin_amdgcn_mfma_f32_16x16x16f16(
                vf, pv[ct][kt], oacc[mi][ct], 0, 0, 0);
        }
      }
    }
    __syncthreads();
  }

  // ---- finalize: per-wave normalized partial + log-sum (no block merge) ----
#pragma unroll
  for (int ct = 0; ct < 3; ++ct) {
    float ls = l4[ct];
    ls += __shfl_xor(ls, 16, 64);
    ls += __shfl_xor(ls, 32, 64);
    const float inv = 1.0f / ls;
    const int rl = w * 48 + ct * 16 + li;
    if (lg == 0) smlp[(size_t)(i0 + rl) * NH + head] = m2[ct] + flog2(ls);
#pragma unroll
    for (int mi = 0; mi < 4; ++mi) {
      v4h o4;
#pragma unroll
      for (int rr = 0; rr < 4; ++rr) o4[rr] = (_Float16)(oacc[mi][ct][rr] * inv);
      *(v4h*)&oPart[(size_t)(i0 + rl) * DM + head * 64 + mi * 16 + lg * 4] = o4;
    }
  }
}

// ---------------- kernel 4: epilogue (j-half merge + transpose + residual) --
extern "C" __global__ __launch_bounds__(256) void epilogue_kernel(
    const _Float16* __restrict__ oP0, const _Float16* __restrict__ oP1,
    const float* __restrict__ sml0, const float* __restrict__ sml1,
    const float* __restrict__ xin, const float* __restrict__ gscal,
    float* __restrict__ outp)
{
  __shared__ float po[8 * 1024];   // 32 KB fp32 merged [row][h*64+x]
  const int tid = threadIdx.x;
  const size_t t0 = (size_t)blockIdx.x * 8;
  {
    const int tr = tid >> 5;
    const int c0 = (tid & 31) * 32;      // within one head's 64-col block
    const int h = c0 >> 6;
    const size_t t = t0 + tr;
    const float s0 = sml0[t * NH + h], s1 = sml1[t * NH + h];
    const float M = fmaxf(s0, s1);
    float u0 = fexp2(s0 - M), u1 = fexp2(s1 - M);
    const float dn = 1.0f / (u0 + u1);
    u0 *= dn; u1 *= dn;
    const _Float16* p0 = oP0 + t * DM + c0;
    const _Float16* p1 = oP1 + t * DM + c0;
#pragma unroll
    for (int c = 0; c < 4; ++c) {
      const v8h a = *(const v8h*)(p0 + c * 8);
      const v8h bb = *(const v8h*)(p1 + c * 8);
      float acc[8];
#pragma unroll
      for (int e = 0; e < 8; ++e)
        acc[e] = u0 * (float)a[e] + u1 * (float)bb[e];
      float4 w0 = {acc[0], acc[1], acc[2], acc[3]};
      float4 w1 = {acc[4], acc[5], acc[6], acc[7]};
      *(float4*)&po[tr * 1024 + c0 + c * 8]     = w0;
      *(float4*)&po[tr * 1024 + c0 + c * 8 + 4] = w1;
    }
  }
  __syncthreads();
  const float g = gscal[0];
  const int tr = tid >> 5;
  const int d0 = (tid & 31) * 32;
  const size_t rb = (t0 + tr) * DM + d0;
#pragma unroll
  for (int c4 = 0; c4 < 8; ++c4) {
    const float4 xi = *(const float4*)&xin[rb + c4 * 4];
    float4 rr;
    rr.x = g * po[tr * 1024 + ((c4 * 4 + 0) & 15) * 64 + ((d0 + c4 * 4 + 0) >> 4)] + xi.x;
    rr.y = g * po[tr * 1024 + ((c4 * 4 + 1) & 15) * 64 + ((d0 + c4 * 4 + 1) >> 4)] + xi.y;
    rr.z = g * po[tr * 1024 + ((c4 * 4 + 2) & 15) * 64 + ((d0 + c4 * 4 + 2) >> 4)] + xi.z;
    rr.w = g * po[tr * 1024 + ((c4 * 4 + 3) & 15) * 64 + ((d0 + c4 * 4 + 3) >> 4)] + xi.w;
    *(float4*)&outp[rb + c4 * 4] = rr;
  }
}

extern "C" void kernel_launch(void* const* d_in, const int* in_sizes, int n_in,
                              void* d_out, int out_size, void* d_ws, size_t ws_size,
                              hipStream_t stream)
{
  const float* x  = (const float*)d_in[0];
  const float* Wq = (const float*)d_in[1];
  const float* bq = (const float*)d_in[2];
  const float* Wk = (const float*)d_in[3];
  const float* bk = (const float*)d_in[4];
  const float* Wv = (const float*)d_in[5];
  const float* bv = (const float*)d_in[6];
  const float* gm = (const float*)d_in[7];
  float* outp = (float*)d_out;
  char* ws = (char*)d_ws;
  const size_t SZH = (size_t)TSEQ * DM * sizeof(_Float16);   // 6 MB
  _Float16* xb   = (_Float16*)(ws);                 // [0,6)   dead after gemm
  _Float16* wb   = (_Float16*)(ws + SZH);           // [6,12)  dead after gemm
  _Float16* qlin = (_Float16*)(ws + 2 * SZH);       // [12,18)
  _Float16* klin = (_Float16*)(ws + 3 * SZH);       // [18,24) dead after repack
  _Float16* vlin = (_Float16*)(ws + 4 * SZH);       // [24,30)
  _Float16* qhp  = (_Float16*)(ws + 5 * SZH);       // [30,36)
  _Float16* khp  = (_Float16*)(ws + 6 * SZH);       // [36,42)
  _Float16* vtp  = (_Float16*)(ws + 7 * SZH);       // [42,48)
  _Float16* oP0  = (_Float16*)(ws);                 // reuses [0,6)  (xb dead)
  _Float16* oP1  = (_Float16*)(ws + SZH);           // reuses [6,12) (wb dead)
  float*    sml0 = (float*)(ws + 3 * SZH);          // reuses klin (dead)
  float*    sml1 = sml0 + (size_t)TSEQ * NH;

  cvt_kernel<<<dim3(2048), dim3(256), 0, stream>>>(x, Wq, Wk, Wv, xb, wb);
  qkv_gemm_kernel<<<dim3(576), dim3(256), 0, stream>>>(xb, wb, bq, bk, bv,
                                                       qlin, klin, vlin);
  repack_kernel<<<dim3(4096), dim3(256), 0, stream>>>(qlin, klin, vlin,
                                                      qhp, khp, vtp);
  attn_kernel<<<dim3(512), dim3(256), 0, stream>>>(qhp, khp, vtp,
                                                   oP0, oP1, sml0, sml1);
  epilogue_kernel<<<dim3(384), dim3(256), 0, stream>>>(oP0, oP1, sml0, sml1,
                                                       x, gm, outp);
  (void)in_sizes; (void)n_in; (void)out_size; (void)ws_size;
}